// Round 2
// baseline (296.799 us; speedup 1.0000x reference)
//
#include <hip/hip_runtime.h>

#define BATCH 16
#define LQ    1024
#define LK    1024
#define DD    512

typedef unsigned int u32;
typedef short short8 __attribute__((ext_vector_type(8)));
typedef float f32x4 __attribute__((ext_vector_type(4)));
typedef u32 u32x2 __attribute__((ext_vector_type(2)));
typedef u32 u32x4 __attribute__((ext_vector_type(4)));
#define AS1 __attribute__((address_space(1)))
#define AS3 __attribute__((address_space(3)))

// ---------------------------------------------------------------------------
// split fp32 pair -> packed bf16 hi (truncation) and bf16 lo (= x - hi)
// ---------------------------------------------------------------------------
__device__ __forceinline__ void split2(float x0, float x1, u32& hp, u32& lp) {
    u32 u0 = __float_as_uint(x0), u1 = __float_as_uint(x1);
    hp = __builtin_amdgcn_perm(u1, u0, 0x07060302u);   // (bf16(x0), bf16(x1))
    float l0 = x0 - __uint_as_float(u0 & 0xffff0000u);
    float l1 = x1 - __uint_as_float(u1 & 0xffff0000u);
    lp = __builtin_amdgcn_perm(__float_as_uint(l1), __float_as_uint(l0), 0x07060302u);
}

// Packed hi/lo layout for a logical [R x K] fp32 matrix (same byte count):
// per row, per 32-k chunk: 16 u32 of hi pairs (k ascending), then 16 u32 of lo.
// u32 offset: row*K + (k0>>5)*32 + pos   (pos in u32 pairs within chunk)

// ---------------------------------------------------------------------------
// Q [16384 x 512] fp32 -> packed hi/lo. 64 threads/row, 8 floats/thread.
// ---------------------------------------------------------------------------
__global__ __launch_bounds__(256) void pack_q(const float* __restrict__ Q,
                                              float* __restrict__ Qhl) {
    const int idx = blockIdx.x * 256 + threadIdx.x;
    const int row = idx >> 6, u = idx & 63;
    const float* src = Q + (size_t)row * DD + u * 8;
    f32x4 a = *(const f32x4*)src;
    f32x4 b = *(const f32x4*)(src + 4);
    u32 h0, h1, h2, h3, l0, l1, l2, l3;
    split2(a[0], a[1], h0, l0);
    split2(a[2], a[3], h1, l1);
    split2(b[0], b[1], h2, l2);
    split2(b[2], b[3], h3, l3);
    u32* dst = (u32*)Qhl + (size_t)row * DD + (u >> 2) * 32 + (u & 3) * 4;
    *(u32x4*)dst        = u32x4{h0, h1, h2, h3};
    *(u32x4*)(dst + 16) = u32x4{l0, l1, l2, l3};
}

// ---------------------------------------------------------------------------
// V [LK x DD] -> packed Vhl [LK x DD] and packed Vthl [DD x LK], per batch.
// grid (DD/32, LK/32, BATCH), 256 threads, 32x32 tile via LDS.
// ---------------------------------------------------------------------------
__global__ __launch_bounds__(256) void transpose_pack_v(const float* __restrict__ V,
                                                        float* __restrict__ Vhl,
                                                        float* __restrict__ Vthl) {
    __shared__ float tile[32][33];
    const int b = blockIdx.z;
    const int c0 = blockIdx.x * 32;   // d
    const int r0 = blockIdx.y * 32;   // kv
    const int t = threadIdx.x;
    const int r = t >> 3, c4 = (t & 7) * 4;
    const float* Vb = V + (size_t)b * LK * DD;
    f32x4 f = *(const f32x4*)(Vb + (size_t)(r0 + r) * DD + c0 + c4);

    // row-major packed (GEMM1 B operand): row = kv, k = d
    u32 h0, l0, h1, l1;
    split2(f[0], f[1], h0, l0);
    split2(f[2], f[3], h1, l1);
    u32* vb = (u32*)Vhl + (size_t)b * LK * DD + (size_t)(r0 + r) * DD
            + (c0 >> 5) * 32 + (t & 7) * 2;
    *(u32x2*)vb        = u32x2{h0, h1};
    *(u32x2*)(vb + 16) = u32x2{l0, l1};

    tile[r][c4 + 0] = f[0]; tile[r][c4 + 1] = f[1];
    tile[r][c4 + 2] = f[2]; tile[r][c4 + 3] = f[3];
    __syncthreads();

    // transposed packed (GEMM2 B operand): row = d, k = kv
    const int n = t >> 3, k4 = (t & 7) * 4;
    f32x4 o = {tile[k4 + 0][n], tile[k4 + 1][n], tile[k4 + 2][n], tile[k4 + 3][n]};
    split2(o[0], o[1], h0, l0);
    split2(o[2], o[3], h1, l1);
    u32* vtb = (u32*)Vthl + (size_t)b * DD * LK + (size_t)(c0 + n) * LK
             + (r0 >> 5) * 32 + (t & 7) * 2;
    *(u32x2*)vtb        = u32x2{h0, h1};
    *(u32x2*)(vtb + 16) = u32x2{l0, l1};
}

// ---------------------------------------------------------------------------
// Pure-MFMA split-bf16 GEMM reading pre-packed hi/lo operands:
//   C[1024 x NG] = A[1024 x KG] * B[NG x KG]^T   per batch
// Same skeleton as the proven gemm_f32split (128x128 tile, BK=32, 4 waves,
// double-buffered LDS, one barrier/K-step, prefetch-before-compute), but the
// inner loop is now {16 ds_read_b128 + 48 MFMA} with zero split VALU.
//
// LDS swizzle (128 B rows = 8 x 16B chunks): phys chunk = logical ^ (row&7).
// Logical chunks 0..3 = hi subchunks (q), 4..7 = lo subchunks (4+q); lane
// (mf,q) reads hi at (q^e)*4, lo at ((4+q)^e)*4, e = mf&7 -> 2 lanes/bank.
// ---------------------------------------------------------------------------
template <int KG, int NG>
__global__ __launch_bounds__(256) void gemm_bf16split(const float* __restrict__ A,
                                                      const float* __restrict__ B,
                                                      float* __restrict__ C) {
    __shared__ float sm[2][2][128 * 32];   // [buf][operand][row*32 + u32] = 64 KB

    const int b   = blockIdx.z;
    const int bm0 = blockIdx.x * 128;
    const int bn0 = blockIdx.y * 128;
    const int tid = threadIdx.x;
    const int w   = tid >> 6;
    const int lane = tid & 63;

    const int op   = w >> 1;
    const int woff = (w & 1) * 64;
    const float* gsrc = (op == 0)
        ? A + (size_t)b * 1024 * KG + (size_t)(bm0 + woff) * KG
        : B + (size_t)b * NG * KG   + (size_t)(bn0 + woff) * KG;
    gsrc += (size_t)(lane >> 3) * KG + (size_t)(((lane & 7) ^ (lane >> 3)) * 4);

    const int mf = lane & 15, q = lane >> 4;
    const int e  = mf & 7;
    const int ch = ((q)     ^ e) * 4;   // float offset of hi subchunk q
    const int cl = ((4 + q) ^ e) * 4;   // float offset of lo subchunk q
    const int wm = (w & 1) * 64, wn = (w >> 1) * 64;

    f32x4 acc[4][4] = {};

    auto stage = [&](int pb, int k) {
#pragma unroll
        for (int t = 0; t < 8; ++t)
            __builtin_amdgcn_global_load_lds((const AS1 u32*)(gsrc + k + (size_t)t * 8 * KG),
                                             (AS3 u32*)(&sm[pb][op][(woff + t * 8) * 32]),
                                             16, 0, 0);
    };

    stage(0, 0);
    int p = 0;
    for (int k0 = 0; k0 < KG; k0 += 32) {
        __syncthreads();                 // drains prefetch into sm[p]; protects sm[p^1]
        if (k0 + 32 < KG) stage(p ^ 1, k0 + 32);

        const float* As = &sm[p][0][0];
        const float* Bs = &sm[p][1][0];
        short8 ah[4], al[4], bh[4], bl[4];
#pragma unroll
        for (int i = 0; i < 4; ++i) {
            const int ra = (wm + mf + i * 16) * 32;
            ah[i] = *(const short8*)&As[ra + ch];
            al[i] = *(const short8*)&As[ra + cl];
            const int rb = (wn + mf + i * 16) * 32;
            bh[i] = *(const short8*)&Bs[rb + ch];
            bl[i] = *(const short8*)&Bs[rb + cl];
        }
#pragma unroll
        for (int i = 0; i < 4; ++i)
#pragma unroll
            for (int j = 0; j < 4; ++j) {
                acc[i][j] = __builtin_amdgcn_mfma_f32_16x16x32_bf16(ah[i], bh[j], acc[i][j], 0, 0, 0);
                acc[i][j] = __builtin_amdgcn_mfma_f32_16x16x32_bf16(ah[i], bl[j], acc[i][j], 0, 0, 0);
                acc[i][j] = __builtin_amdgcn_mfma_f32_16x16x32_bf16(al[i], bh[j], acc[i][j], 0, 0, 0);
            }
        p ^= 1;
    }

    // epilogue: C/D layout col = lane&15, row = q*4 + reg  [m89-verified]
    float* Cb = C + (size_t)b * 1024 * NG + (size_t)bm0 * NG + bn0;
#pragma unroll
    for (int i = 0; i < 4; ++i)
#pragma unroll
        for (int j = 0; j < 4; ++j)
#pragma unroll
            for (int r = 0; r < 4; ++r)
                Cb[(size_t)(wm + i * 16 + q * 4 + r) * NG + wn + j * 16 + mf] = acc[i][j][r];
}

// ---------------------------------------------------------------------------
// Row softmax in place + pack P hi/lo. 16384 rows of 1024. One block per row.
// ---------------------------------------------------------------------------
__global__ __launch_bounds__(256) void softmax_rows_pack(float* __restrict__ S,
                                                         float* __restrict__ Phl) {
    float* p = S + (size_t)blockIdx.x * LK;
    const int t = threadIdx.x;
    f32x4 v = *(f32x4*)(p + (t << 2));
    float m = fmaxf(fmaxf(v[0], v[1]), fmaxf(v[2], v[3]));
#pragma unroll
    for (int off = 1; off < 64; off <<= 1) m = fmaxf(m, __shfl_xor(m, off, 64));
    __shared__ float redm[4]; __shared__ float reds[4];
    const int wave = t >> 6, lane = t & 63;
    if (lane == 0) redm[wave] = m;
    __syncthreads();
    m = fmaxf(fmaxf(redm[0], redm[1]), fmaxf(redm[2], redm[3]));
    v[0] = __expf(v[0] - m); v[1] = __expf(v[1] - m);
    v[2] = __expf(v[2] - m); v[3] = __expf(v[3] - m);
    float s = (v[0] + v[1]) + (v[2] + v[3]);
#pragma unroll
    for (int off = 1; off < 64; off <<= 1) s += __shfl_xor(s, off, 64);
    if (lane == 0) reds[wave] = s;
    __syncthreads();
    s = (reds[0] + reds[1]) + (reds[2] + reds[3]);
    const float inv = 1.0f / s;
    v[0] *= inv; v[1] *= inv; v[2] *= inv; v[3] *= inv;
    *(f32x4*)(p + (t << 2)) = v;
    // pack for GEMM2 A operand
    u32 h0, l0, h1, l1;
    split2(v[0], v[1], h0, l0);
    split2(v[2], v[3], h1, l1);
    u32* prow = (u32*)Phl + (size_t)blockIdx.x * LK + (t >> 3) * 32 + (t & 7) * 2;
    *(u32x2*)prow        = u32x2{h0, h1};
    *(u32x2*)(prow + 16) = u32x2{l0, l1};
}

// ===========================================================================
// Fallback path A (ws >= 33.6 MB): previous verified in-GEMM-split kernels
// ===========================================================================
__global__ __launch_bounds__(256) void transpose_v(const float* __restrict__ V,
                                                   float* __restrict__ Vt) {
    __shared__ float tile[32][33];
    const int b = blockIdx.z;
    const int c0 = blockIdx.x * 32;
    const int r0 = blockIdx.y * 32;
    const int t = threadIdx.x;
    const int r = t >> 3, c4 = (t & 7) * 4;
    const float* Vb = V + (size_t)b * LK * DD;
    float4 f = *(const float4*)(Vb + (size_t)(r0 + r) * DD + c0 + c4);
    tile[r][c4 + 0] = f.x; tile[r][c4 + 1] = f.y;
    tile[r][c4 + 2] = f.z; tile[r][c4 + 3] = f.w;
    __syncthreads();
    const int n = t >> 3, k4 = (t & 7) * 4;
    float4 o = {tile[k4 + 0][n], tile[k4 + 1][n], tile[k4 + 2][n], tile[k4 + 3][n]};
    *(float4*)(Vt + (size_t)b * DD * LK + (size_t)(c0 + n) * LK + r0 + k4) = o;
}

__device__ __forceinline__ void mk_frags(f32x4 f0, f32x4 f1, short8& h, short8& l) {
    union { u32 u[4]; short8 s; } H, L;
    split2(f0[0], f0[1], H.u[0], L.u[0]);
    split2(f0[2], f0[3], H.u[1], L.u[1]);
    split2(f1[0], f1[1], H.u[2], L.u[2]);
    split2(f1[2], f1[3], H.u[3], L.u[3]);
    h = H.s; l = L.s;
}

template <int KG, int NG>
__global__ __launch_bounds__(256) void gemm_f32split(const float* __restrict__ A,
                                                     const float* __restrict__ B,
                                                     float* __restrict__ C) {
    __shared__ float sm[2][2][128 * 32];
    const int b   = blockIdx.z;
    const int bm0 = blockIdx.x * 128;
    const int bn0 = blockIdx.y * 128;
    const int tid = threadIdx.x;
    const int w   = tid >> 6;
    const int lane = tid & 63;
    const int op   = w >> 1;
    const int woff = (w & 1) * 64;
    const float* gsrc = (op == 0)
        ? A + (size_t)b * 1024 * KG + (size_t)(bm0 + woff) * KG
        : B + (size_t)b * NG * KG   + (size_t)(bn0 + woff) * KG;
    gsrc += (size_t)(lane >> 3) * KG + (size_t)(((lane & 7) ^ (lane >> 3)) * 4);
    const int mf = lane & 15, q = lane >> 4;
    const int e  = mf & 7;
    const int c0 = ((2 * q) ^ e) * 4;
    const int c1 = ((2 * q + 1) ^ e) * 4;
    const int wm = (w & 1) * 64, wn = (w >> 1) * 64;
    f32x4 acc[4][4] = {};
    auto stage = [&](int pb, int k) {
#pragma unroll
        for (int t = 0; t < 8; ++t)
            __builtin_amdgcn_global_load_lds((const AS1 u32*)(gsrc + k + (size_t)t * 8 * KG),
                                             (AS3 u32*)(&sm[pb][op][(woff + t * 8) * 32]),
                                             16, 0, 0);
    };
    stage(0, 0);
    int p = 0;
    for (int k0 = 0; k0 < KG; k0 += 32) {
        __syncthreads();
        if (k0 + 32 < KG) stage(p ^ 1, k0 + 32);
        const float* As = &sm[p][0][0];
        const float* Bs = &sm[p][1][0];
        short8 ah[4], al[4], bh[4], bl[4];
#pragma unroll
        for (int i = 0; i < 4; ++i) {
            const int ra = (wm + mf + i * 16) * 32;
            f32x4 f0 = *(const f32x4*)&As[ra + c0];
            f32x4 f1 = *(const f32x4*)&As[ra + c1];
            mk_frags(f0, f1, ah[i], al[i]);
            const int rb = (wn + mf + i * 16) * 32;
            f32x4 g0 = *(const f32x4*)&Bs[rb + c0];
            f32x4 g1 = *(const f32x4*)&Bs[rb + c1];
            mk_frags(g0, g1, bh[i], bl[i]);
        }
#pragma unroll
        for (int i = 0; i < 4; ++i)
#pragma unroll
            for (int j = 0; j < 4; ++j) {
                acc[i][j] = __builtin_amdgcn_mfma_f32_16x16x32_bf16(ah[i], bh[j], acc[i][j], 0, 0, 0);
                acc[i][j] = __builtin_amdgcn_mfma_f32_16x16x32_bf16(ah[i], bl[j], acc[i][j], 0, 0, 0);
                acc[i][j] = __builtin_amdgcn_mfma_f32_16x16x32_bf16(al[i], bh[j], acc[i][j], 0, 0, 0);
            }
        p ^= 1;
    }
    float* Cb = C + (size_t)b * 1024 * NG + (size_t)bm0 * NG + bn0;
#pragma unroll
    for (int i = 0; i < 4; ++i)
#pragma unroll
        for (int j = 0; j < 4; ++j)
#pragma unroll
            for (int r = 0; r < 4; ++r)
                Cb[(size_t)(wm + i * 16 + q * 4 + r) * NG + wn + j * 16 + mf] = acc[i][j][r];
}

__global__ __launch_bounds__(256) void softmax_rows(float* __restrict__ S) {
    float* p = S + (size_t)blockIdx.x * LK;
    const int t = threadIdx.x;
    float4 v = *(float4*)(p + (t << 2));
    float m = fmaxf(fmaxf(v.x, v.y), fmaxf(v.z, v.w));
#pragma unroll
    for (int off = 1; off < 64; off <<= 1) m = fmaxf(m, __shfl_xor(m, off, 64));
    __shared__ float redm[4]; __shared__ float reds[4];
    const int wave = t >> 6, lane = t & 63;
    if (lane == 0) redm[wave] = m;
    __syncthreads();
    m = fmaxf(fmaxf(redm[0], redm[1]), fmaxf(redm[2], redm[3]));
    v.x = __expf(v.x - m); v.y = __expf(v.y - m);
    v.z = __expf(v.z - m); v.w = __expf(v.w - m);
    float s = (v.x + v.y) + (v.z + v.w);
#pragma unroll
    for (int off = 1; off < 64; off <<= 1) s += __shfl_xor(s, off, 64);
    if (lane == 0) reds[wave] = s;
    __syncthreads();
    s = (reds[0] + reds[1]) + (reds[2] + reds[3]);
    const float inv = 1.0f / s;
    v.x *= inv; v.y *= inv; v.z *= inv; v.w *= inv;
    *(float4*)(p + (t << 2)) = v;
}

// ===========================================================================
// Fallback path B (tiny ws): plain fp32 tiled GEMMs
// ===========================================================================
constexpr int BM = 64, BN = 64, BK = 16, PAD = 4;

__global__ __launch_bounds__(256) void gemm_qvt(const float* __restrict__ Q,
                                                const float* __restrict__ V,
                                                float* __restrict__ S) {
    __shared__ __align__(16) float sA[BK][BM + PAD];
    __shared__ __align__(16) float sB[BK][BN + PAD];
    const int b = blockIdx.z;
    const float* Qb = Q + (size_t)b * LQ * DD + (size_t)blockIdx.x * BM * DD;
    const float* Vb = V + (size_t)b * LK * DD + (size_t)blockIdx.y * BN * DD;
    float*       Sb = S + (size_t)b * LQ * LK;
    const int tid = threadIdx.x;
    const int tx = tid & 15, ty = tid >> 4;
    const int lr = tid >> 2, lc = (tid & 3) << 2;
    float acc[4][4] = {};
    for (int k0 = 0; k0 < DD; k0 += BK) {
        float4 qa = *(const float4*)(Qb + (size_t)lr * DD + k0 + lc);
        float4 va = *(const float4*)(Vb + (size_t)lr * DD + k0 + lc);
        __syncthreads();
        sA[lc + 0][lr] = qa.x; sA[lc + 1][lr] = qa.y; sA[lc + 2][lr] = qa.z; sA[lc + 3][lr] = qa.w;
        sB[lc + 0][lr] = va.x; sB[lc + 1][lr] = va.y; sB[lc + 2][lr] = va.z; sB[lc + 3][lr] = va.w;
        __syncthreads();
#pragma unroll
        for (int k = 0; k < BK; ++k) {
            float4 a4 = *(const float4*)&sA[k][ty << 2];
            float4 b4 = *(const float4*)&sB[k][tx << 2];
            float a[4] = {a4.x, a4.y, a4.z, a4.w};
            float bb[4] = {b4.x, b4.y, b4.z, b4.w};
#pragma unroll
            for (int i = 0; i < 4; ++i)
#pragma unroll
                for (int j = 0; j < 4; ++j) acc[i][j] = fmaf(a[i], bb[j], acc[i][j]);
        }
    }
    const int r0 = blockIdx.x * BM + (ty << 2), c0 = blockIdx.y * BN + (tx << 2);
#pragma unroll
    for (int i = 0; i < 4; ++i) {
        float4 o = {acc[i][0], acc[i][1], acc[i][2], acc[i][3]};
        *(float4*)(Sb + (size_t)(r0 + i) * LK + c0) = o;
    }
}

__global__ __launch_bounds__(256) void gemm_pv(const float* __restrict__ P,
                                               const float* __restrict__ V,
                                               float* __restrict__ C) {
    __shared__ __align__(16) float sA[BK][BM + PAD];
    __shared__ __align__(16) float sB[BK][BN + PAD];
    const int b = blockIdx.z;
    const float* Pb = P + (size_t)b * LQ * LK + (size_t)blockIdx.x * BM * LK;
    const float* Vb = V + (size_t)b * LK * DD;
    float*       Cb = C + (size_t)b * LQ * DD;
    const int tid = threadIdx.x;
    const int tx = tid & 15, ty = tid >> 4;
    const int lr = tid >> 2, lc = (tid & 3) << 2;
    const int bkr = tid >> 4, bcg = (tid & 15) << 2;
    const int n0 = blockIdx.y * BN;
    float acc[4][4] = {};
    for (int k0 = 0; k0 < LK; k0 += BK) {
        float4 pa = *(const float4*)(Pb + (size_t)lr * LK + k0 + lc);
        float4 vb = *(const float4*)(Vb + (size_t)(k0 + bkr) * DD + n0 + bcg);
        __syncthreads();
        sA[lc + 0][lr] = pa.x; sA[lc + 1][lr] = pa.y; sA[lc + 2][lr] = pa.z; sA[lc + 3][lr] = pa.w;
        *(float4*)&sB[bkr][bcg] = vb;
        __syncthreads();
#pragma unroll
        for (int k = 0; k < BK; ++k) {
            float4 a4 = *(const float4*)&sA[k][ty << 2];
            float4 b4 = *(const float4*)&sB[k][tx << 2];
            float a[4] = {a4.x, a4.y, a4.z, a4.w};
            float bb[4] = {b4.x, b4.y, b4.z, b4.w};
#pragma unroll
            for (int i = 0; i < 4; ++i)
#pragma unroll
                for (int j = 0; j < 4; ++j) acc[i][j] = fmaf(a[i], bb[j], acc[i][j]);
        }
    }
    const int r0 = blockIdx.x * BM + (ty << 2), c0 = n0 + (tx << 2);
#pragma unroll
    for (int i = 0; i < 4; ++i) {
        float4 o = {acc[i][0], acc[i][1], acc[i][2], acc[i][3]};
        *(float4*)(Cb + (size_t)(r0 + i) * DD + c0) = o;
    }
}

// ---------------------------------------------------------------------------
extern "C" void kernel_launch(void* const* d_in, const int* in_sizes, int n_in,
                              void* d_out, int out_size, void* d_ws, size_t ws_size,
                              hipStream_t stream) {
    const float* Q = (const float*)d_in[0];
    const float* V = (const float*)d_in[1];

    float* ctx  = (float*)d_out;                       // [16,1024,512]
    float* attn = ctx + (size_t)BATCH * LQ * DD;       // [16,1024,1024]

    const size_t qv_elems = (size_t)BATCH * LQ * DD;   // 8.4M u32 = 33.55 MB
    const size_t p_elems  = (size_t)BATCH * LQ * LK;   // 16.8M u32 = 67.1 MB
    const size_t need_new = (3 * qv_elems + p_elems) * sizeof(float);  // 167.8 MB

    if (ws_size >= need_new) {
        float* Qhl  = (float*)d_ws;
        float* Vhl  = Qhl  + qv_elems;
        float* Vthl = Vhl  + qv_elems;
        float* Phl  = Vthl + qv_elems;
        pack_q<<<dim3(BATCH * LQ * DD / (8 * 256)), 256, 0, stream>>>(Q, Qhl);
        transpose_pack_v<<<dim3(DD / 32, LK / 32, BATCH), 256, 0, stream>>>(V, Vhl, Vthl);
        // S = Q @ V^T : A = Qhl [1024,512], B = Vhl [1024,512]
        gemm_bf16split<DD, LK><<<dim3(8, 8, BATCH), 256, 0, stream>>>(Qhl, Vhl, attn);
        softmax_rows_pack<<<dim3(BATCH * LQ), 256, 0, stream>>>(attn, Phl);
        // ctx = P @ V : A = Phl [1024,1024], B = Vthl [512,1024]
        gemm_bf16split<LK, DD><<<dim3(8, 4, BATCH), 256, 0, stream>>>(Phl, Vthl, ctx);
    } else if (ws_size >= qv_elems * sizeof(float)) {
        float* Vt = (float*)d_ws;
        transpose_v<<<dim3(DD / 32, LK / 32, BATCH), 256, 0, stream>>>(V, Vt);
        gemm_f32split<DD, LK><<<dim3(8, 8, BATCH), 256, 0, stream>>>(Q, V, attn);
        softmax_rows<<<dim3(BATCH * LQ), 256, 0, stream>>>(attn);
        gemm_f32split<LK, DD><<<dim3(8, 4, BATCH), 256, 0, stream>>>(attn, Vt, ctx);
    } else {
        gemm_qvt<<<dim3(LQ / BM, LK / BN, BATCH), 256, 0, stream>>>(Q, V, attn);
        softmax_rows<<<dim3(BATCH * LQ), 256, 0, stream>>>(attn);
        gemm_pv<<<dim3(LQ / BM, DD / BN, BATCH), 256, 0, stream>>>(attn, V, ctx);
    }
}

// Round 3
// 294.060 us; speedup vs baseline: 1.0093x; 1.0093x over previous
//
#include <hip/hip_runtime.h>

#define BATCH 16
#define LQ    1024
#define LK    1024
#define DD    512

typedef unsigned int u32;
typedef short short8 __attribute__((ext_vector_type(8)));
typedef float f32x4 __attribute__((ext_vector_type(4)));
typedef u32 u32x2 __attribute__((ext_vector_type(2)));
typedef u32 u32x4 __attribute__((ext_vector_type(4)));
#define AS1 __attribute__((address_space(1)))
#define AS3 __attribute__((address_space(3)))

// ---------------------------------------------------------------------------
// split fp32 pair -> packed bf16 hi (truncation) and bf16 lo (= x - hi)
// ---------------------------------------------------------------------------
__device__ __forceinline__ void split2(float x0, float x1, u32& hp, u32& lp) {
    u32 u0 = __float_as_uint(x0), u1 = __float_as_uint(x1);
    hp = __builtin_amdgcn_perm(u1, u0, 0x07060302u);   // (bf16(x0), bf16(x1))
    float l0 = x0 - __uint_as_float(u0 & 0xffff0000u);
    float l1 = x1 - __uint_as_float(u1 & 0xffff0000u);
    lp = __builtin_amdgcn_perm(__float_as_uint(l1), __float_as_uint(l0), 0x07060302u);
}

// Packed hi/lo layout for a logical [R x K] fp32 matrix (same byte count):
// per row, per 32-k chunk: 16 u32 of hi pairs (k ascending), then 16 u32 of lo.
// u32 offset: row*K + (k0>>5)*32 + pos   (pos in u32 pairs within chunk)

// ---------------------------------------------------------------------------
// Q [16384 x 512] fp32 -> packed hi/lo. 64 threads/row, 8 floats/thread.
// ---------------------------------------------------------------------------
__global__ __launch_bounds__(256) void pack_q(const float* __restrict__ Q,
                                              float* __restrict__ Qhl) {
    const int idx = blockIdx.x * 256 + threadIdx.x;
    const int row = idx >> 6, u = idx & 63;
    const float* src = Q + (size_t)row * DD + u * 8;
    f32x4 a = *(const f32x4*)src;
    f32x4 b = *(const f32x4*)(src + 4);
    u32 h0, h1, h2, h3, l0, l1, l2, l3;
    split2(a[0], a[1], h0, l0);
    split2(a[2], a[3], h1, l1);
    split2(b[0], b[1], h2, l2);
    split2(b[2], b[3], h3, l3);
    u32* dst = (u32*)Qhl + (size_t)row * DD + (u >> 2) * 32 + (u & 3) * 4;
    *(u32x4*)dst        = u32x4{h0, h1, h2, h3};
    *(u32x4*)(dst + 16) = u32x4{l0, l1, l2, l3};
}

// ---------------------------------------------------------------------------
// V [LK x DD] -> packed Vhl [LK x DD] and packed Vthl [DD x LK], per batch.
// grid (DD/32, LK/32, BATCH), 256 threads, 32x32 tile via LDS.
// ---------------------------------------------------------------------------
__global__ __launch_bounds__(256) void transpose_pack_v(const float* __restrict__ V,
                                                        float* __restrict__ Vhl,
                                                        float* __restrict__ Vthl) {
    __shared__ float tile[32][33];
    const int b = blockIdx.z;
    const int c0 = blockIdx.x * 32;   // d
    const int r0 = blockIdx.y * 32;   // kv
    const int t = threadIdx.x;
    const int r = t >> 3, c4 = (t & 7) * 4;
    const float* Vb = V + (size_t)b * LK * DD;
    f32x4 f = *(const f32x4*)(Vb + (size_t)(r0 + r) * DD + c0 + c4);

    // row-major packed (GEMM1 B operand): row = kv, k = d
    u32 h0, l0, h1, l1;
    split2(f[0], f[1], h0, l0);
    split2(f[2], f[3], h1, l1);
    u32* vb = (u32*)Vhl + (size_t)b * LK * DD + (size_t)(r0 + r) * DD
            + (c0 >> 5) * 32 + (t & 7) * 2;
    *(u32x2*)vb        = u32x2{h0, h1};
    *(u32x2*)(vb + 16) = u32x2{l0, l1};

    tile[r][c4 + 0] = f[0]; tile[r][c4 + 1] = f[1];
    tile[r][c4 + 2] = f[2]; tile[r][c4 + 3] = f[3];
    __syncthreads();

    // transposed packed (GEMM2 B operand): row = d, k = kv
    const int n = t >> 3, k4 = (t & 7) * 4;
    f32x4 o = {tile[k4 + 0][n], tile[k4 + 1][n], tile[k4 + 2][n], tile[k4 + 3][n]};
    split2(o[0], o[1], h0, l0);
    split2(o[2], o[3], h1, l1);
    u32* vtb = (u32*)Vthl + (size_t)b * DD * LK + (size_t)(c0 + n) * LK
             + (r0 >> 5) * 32 + (t & 7) * 2;
    *(u32x2*)vtb        = u32x2{h0, h1};
    *(u32x2*)(vtb + 16) = u32x2{l0, l1};
}

// ---------------------------------------------------------------------------
// Pure-MFMA split-bf16 GEMM reading pre-packed hi/lo operands:
//   C[1024 x NG] = A[1024 x KG] * B[NG x KG]^T   per batch
// NPROD=3: acc += Ah*Bh + Ah*Bl + Al*Bh   (full split product)
// NPROD=2: acc += Ah*Bh + Ah*Bl           (A treated as hi-only; used for P@V
//          where P in [0,1] makes the Al term ~1.5e-3 abs on ctx — negligible)
//
// 128x128 tile, BK=32, 4 waves, double-buffered LDS (2 x 32 KB), one barrier
// per K-step with prefetch issued before compute.
// LDS swizzle (128 B rows = 8 x 16B chunks): phys chunk = logical ^ (row&7).
// ---------------------------------------------------------------------------
template <int KG, int NG, int NPROD>
__global__ __launch_bounds__(256) void gemm_bf16split(const float* __restrict__ A,
                                                      const float* __restrict__ B,
                                                      float* __restrict__ C) {
    __shared__ float sm[2][2][128 * 32];   // [buf][operand][row*32 + u32] = 64 KB

    const int b   = blockIdx.z;
    const int bm0 = blockIdx.x * 128;
    const int bn0 = blockIdx.y * 128;
    const int tid = threadIdx.x;
    const int w   = tid >> 6;
    const int lane = tid & 63;

    const int op   = w >> 1;
    const int woff = (w & 1) * 64;
    const float* gsrc = (op == 0)
        ? A + (size_t)b * 1024 * KG + (size_t)(bm0 + woff) * KG
        : B + (size_t)b * NG * KG   + (size_t)(bn0 + woff) * KG;
    gsrc += (size_t)(lane >> 3) * KG + (size_t)(((lane & 7) ^ (lane >> 3)) * 4);

    const int mf = lane & 15, q = lane >> 4;
    const int e  = mf & 7;
    const int ch = ((q)     ^ e) * 4;   // float offset of hi subchunk q
    const int cl = ((4 + q) ^ e) * 4;   // float offset of lo subchunk q
    const int wm = (w & 1) * 64, wn = (w >> 1) * 64;

    f32x4 acc[4][4] = {};

    auto stage = [&](int pb, int k) {
#pragma unroll
        for (int t = 0; t < 8; ++t)
            __builtin_amdgcn_global_load_lds((const AS1 u32*)(gsrc + k + (size_t)t * 8 * KG),
                                             (AS3 u32*)(&sm[pb][op][(woff + t * 8) * 32]),
                                             16, 0, 0);
    };

    stage(0, 0);
    int p = 0;
    for (int k0 = 0; k0 < KG; k0 += 32) {
        __syncthreads();                 // drains prefetch into sm[p]; protects sm[p^1]
        if (k0 + 32 < KG) stage(p ^ 1, k0 + 32);

        const float* As = &sm[p][0][0];
        const float* Bs = &sm[p][1][0];
        short8 ah[4], al[4], bh[4], bl[4];
#pragma unroll
        for (int i = 0; i < 4; ++i) {
            const int ra = (wm + mf + i * 16) * 32;
            ah[i] = *(const short8*)&As[ra + ch];
            if constexpr (NPROD == 3) al[i] = *(const short8*)&As[ra + cl];
            const int rb = (wn + mf + i * 16) * 32;
            bh[i] = *(const short8*)&Bs[rb + ch];
            bl[i] = *(const short8*)&Bs[rb + cl];
        }
#pragma unroll
        for (int i = 0; i < 4; ++i)
#pragma unroll
            for (int j = 0; j < 4; ++j) {
                acc[i][j] = __builtin_amdgcn_mfma_f32_16x16x32_bf16(ah[i], bh[j], acc[i][j], 0, 0, 0);
                acc[i][j] = __builtin_amdgcn_mfma_f32_16x16x32_bf16(ah[i], bl[j], acc[i][j], 0, 0, 0);
                if constexpr (NPROD == 3)
                    acc[i][j] = __builtin_amdgcn_mfma_f32_16x16x32_bf16(al[i], bh[j], acc[i][j], 0, 0, 0);
            }
        p ^= 1;
    }

    // epilogue: C/D layout col = lane&15, row = q*4 + reg  [m89-verified]
    float* Cb = C + (size_t)b * 1024 * NG + (size_t)bm0 * NG + bn0;
#pragma unroll
    for (int i = 0; i < 4; ++i)
#pragma unroll
        for (int j = 0; j < 4; ++j)
#pragma unroll
            for (int r = 0; r < 4; ++r)
                Cb[(size_t)(wm + i * 16 + q * 4 + r) * NG + wn + j * 16 + mf] = acc[i][j][r];
}

// ---------------------------------------------------------------------------
// Barrier-free row softmax + pack: one wave per row (16 floats/lane in regs),
// 4 rows per block, pure shuffle reductions. 16384 rows -> 4096 blocks.
// ---------------------------------------------------------------------------
__global__ __launch_bounds__(256) void softmax_rows_pack2(float* __restrict__ S,
                                                          float* __restrict__ Phl) {
    const int t = threadIdx.x;
    const int wave = t >> 6, lane = t & 63;
    const size_t row = (size_t)blockIdx.x * 4 + wave;
    float* p = S + row * LK;
    f32x4 v[4];
#pragma unroll
    for (int c = 0; c < 4; ++c)
        v[c] = *(const f32x4*)(p + lane * 4 + c * 256);
    float m = -1e30f;
#pragma unroll
    for (int c = 0; c < 4; ++c)
        m = fmaxf(m, fmaxf(fmaxf(v[c][0], v[c][1]), fmaxf(v[c][2], v[c][3])));
#pragma unroll
    for (int off = 1; off < 64; off <<= 1) m = fmaxf(m, __shfl_xor(m, off, 64));
    float s = 0.0f;
#pragma unroll
    for (int c = 0; c < 4; ++c) {
        v[c][0] = __expf(v[c][0] - m);
        v[c][1] = __expf(v[c][1] - m);
        v[c][2] = __expf(v[c][2] - m);
        v[c][3] = __expf(v[c][3] - m);
        s += (v[c][0] + v[c][1]) + (v[c][2] + v[c][3]);
    }
#pragma unroll
    for (int off = 1; off < 64; off <<= 1) s += __shfl_xor(s, off, 64);
    const float inv = 1.0f / s;
    u32* prow = (u32*)Phl + row * LK;
#pragma unroll
    for (int c = 0; c < 4; ++c) {
        v[c] = v[c] * inv;
        *(f32x4*)(p + lane * 4 + c * 256) = v[c];
        u32 h0, l0, h1, l1;
        split2(v[c][0], v[c][1], h0, l0);
        split2(v[c][2], v[c][3], h1, l1);
        u32* d = prow + ((lane >> 3) + 8 * c) * 32 + (lane & 7) * 2;
        *(u32x2*)d        = u32x2{h0, h1};
        *(u32x2*)(d + 16) = u32x2{l0, l1};
    }
}

// ===========================================================================
// Fallback path A (ws >= 33.6 MB): previous verified in-GEMM-split kernels
// ===========================================================================
__global__ __launch_bounds__(256) void transpose_v(const float* __restrict__ V,
                                                   float* __restrict__ Vt) {
    __shared__ float tile[32][33];
    const int b = blockIdx.z;
    const int c0 = blockIdx.x * 32;
    const int r0 = blockIdx.y * 32;
    const int t = threadIdx.x;
    const int r = t >> 3, c4 = (t & 7) * 4;
    const float* Vb = V + (size_t)b * LK * DD;
    float4 f = *(const float4*)(Vb + (size_t)(r0 + r) * DD + c0 + c4);
    tile[r][c4 + 0] = f.x; tile[r][c4 + 1] = f.y;
    tile[r][c4 + 2] = f.z; tile[r][c4 + 3] = f.w;
    __syncthreads();
    const int n = t >> 3, k4 = (t & 7) * 4;
    float4 o = {tile[k4 + 0][n], tile[k4 + 1][n], tile[k4 + 2][n], tile[k4 + 3][n]};
    *(float4*)(Vt + (size_t)b * DD * LK + (size_t)(c0 + n) * LK + r0 + k4) = o;
}

__device__ __forceinline__ void mk_frags(f32x4 f0, f32x4 f1, short8& h, short8& l) {
    union { u32 u[4]; short8 s; } H, L;
    split2(f0[0], f0[1], H.u[0], L.u[0]);
    split2(f0[2], f0[3], H.u[1], L.u[1]);
    split2(f1[0], f1[1], H.u[2], L.u[2]);
    split2(f1[2], f1[3], H.u[3], L.u[3]);
    h = H.s; l = L.s;
}

template <int KG, int NG>
__global__ __launch_bounds__(256) void gemm_f32split(const float* __restrict__ A,
                                                     const float* __restrict__ B,
                                                     float* __restrict__ C) {
    __shared__ float sm[2][2][128 * 32];
    const int b   = blockIdx.z;
    const int bm0 = blockIdx.x * 128;
    const int bn0 = blockIdx.y * 128;
    const int tid = threadIdx.x;
    const int w   = tid >> 6;
    const int lane = tid & 63;
    const int op   = w >> 1;
    const int woff = (w & 1) * 64;
    const float* gsrc = (op == 0)
        ? A + (size_t)b * 1024 * KG + (size_t)(bm0 + woff) * KG
        : B + (size_t)b * NG * KG   + (size_t)(bn0 + woff) * KG;
    gsrc += (size_t)(lane >> 3) * KG + (size_t)(((lane & 7) ^ (lane >> 3)) * 4);
    const int mf = lane & 15, q = lane >> 4;
    const int e  = mf & 7;
    const int c0 = ((2 * q) ^ e) * 4;
    const int c1 = ((2 * q + 1) ^ e) * 4;
    const int wm = (w & 1) * 64, wn = (w >> 1) * 64;
    f32x4 acc[4][4] = {};
    auto stage = [&](int pb, int k) {
#pragma unroll
        for (int t = 0; t < 8; ++t)
            __builtin_amdgcn_global_load_lds((const AS1 u32*)(gsrc + k + (size_t)t * 8 * KG),
                                             (AS3 u32*)(&sm[pb][op][(woff + t * 8) * 32]),
                                             16, 0, 0);
    };
    stage(0, 0);
    int p = 0;
    for (int k0 = 0; k0 < KG; k0 += 32) {
        __syncthreads();
        if (k0 + 32 < KG) stage(p ^ 1, k0 + 32);
        const float* As = &sm[p][0][0];
        const float* Bs = &sm[p][1][0];
        short8 ah[4], al[4], bh[4], bl[4];
#pragma unroll
        for (int i = 0; i < 4; ++i) {
            const int ra = (wm + mf + i * 16) * 32;
            f32x4 f0 = *(const f32x4*)&As[ra + c0];
            f32x4 f1 = *(const f32x4*)&As[ra + c1];
            mk_frags(f0, f1, ah[i], al[i]);
            const int rb = (wn + mf + i * 16) * 32;
            f32x4 g0 = *(const f32x4*)&Bs[rb + c0];
            f32x4 g1 = *(const f32x4*)&Bs[rb + c1];
            mk_frags(g0, g1, bh[i], bl[i]);
        }
#pragma unroll
        for (int i = 0; i < 4; ++i)
#pragma unroll
            for (int j = 0; j < 4; ++j) {
                acc[i][j] = __builtin_amdgcn_mfma_f32_16x16x32_bf16(ah[i], bh[j], acc[i][j], 0, 0, 0);
                acc[i][j] = __builtin_amdgcn_mfma_f32_16x16x32_bf16(ah[i], bl[j], acc[i][j], 0, 0, 0);
                acc[i][j] = __builtin_amdgcn_mfma_f32_16x16x32_bf16(al[i], bh[j], acc[i][j], 0, 0, 0);
            }
        p ^= 1;
    }
    float* Cb = C + (size_t)b * 1024 * NG + (size_t)bm0 * NG + bn0;
#pragma unroll
    for (int i = 0; i < 4; ++i)
#pragma unroll
        for (int j = 0; j < 4; ++j)
#pragma unroll
            for (int r = 0; r < 4; ++r)
                Cb[(size_t)(wm + i * 16 + q * 4 + r) * NG + wn + j * 16 + mf] = acc[i][j][r];
}

__global__ __launch_bounds__(256) void softmax_rows(float* __restrict__ S) {
    float* p = S + (size_t)blockIdx.x * LK;
    const int t = threadIdx.x;
    float4 v = *(float4*)(p + (t << 2));
    float m = fmaxf(fmaxf(v.x, v.y), fmaxf(v.z, v.w));
#pragma unroll
    for (int off = 1; off < 64; off <<= 1) m = fmaxf(m, __shfl_xor(m, off, 64));
    __shared__ float redm[4]; __shared__ float reds[4];
    const int wave = t >> 6, lane = t & 63;
    if (lane == 0) redm[wave] = m;
    __syncthreads();
    m = fmaxf(fmaxf(redm[0], redm[1]), fmaxf(redm[2], redm[3]));
    v.x = __expf(v.x - m); v.y = __expf(v.y - m);
    v.z = __expf(v.z - m); v.w = __expf(v.w - m);
    float s = (v.x + v.y) + (v.z + v.w);
#pragma unroll
    for (int off = 1; off < 64; off <<= 1) s += __shfl_xor(s, off, 64);
    if (lane == 0) reds[wave] = s;
    __syncthreads();
    s = (reds[0] + reds[1]) + (reds[2] + reds[3]);
    const float inv = 1.0f / s;
    v.x *= inv; v.y *= inv; v.z *= inv; v.w *= inv;
    *(float4*)(p + (t << 2)) = v;
}

// ===========================================================================
// Fallback path B (tiny ws): plain fp32 tiled GEMMs
// ===========================================================================
constexpr int BM = 64, BN = 64, BK = 16, PAD = 4;

__global__ __launch_bounds__(256) void gemm_qvt(const float* __restrict__ Q,
                                                const float* __restrict__ V,
                                                float* __restrict__ S) {
    __shared__ __align__(16) float sA[BK][BM + PAD];
    __shared__ __align__(16) float sB[BK][BN + PAD];
    const int b = blockIdx.z;
    const float* Qb = Q + (size_t)b * LQ * DD + (size_t)blockIdx.x * BM * DD;
    const float* Vb = V + (size_t)b * LK * DD + (size_t)blockIdx.y * BN * DD;
    float*       Sb = S + (size_t)b * LQ * LK;
    const int tid = threadIdx.x;
    const int tx = tid & 15, ty = tid >> 4;
    const int lr = tid >> 2, lc = (tid & 3) << 2;
    float acc[4][4] = {};
    for (int k0 = 0; k0 < DD; k0 += BK) {
        float4 qa = *(const float4*)(Qb + (size_t)lr * DD + k0 + lc);
        float4 va = *(const float4*)(Vb + (size_t)lr * DD + k0 + lc);
        __syncthreads();
        sA[lc + 0][lr] = qa.x; sA[lc + 1][lr] = qa.y; sA[lc + 2][lr] = qa.z; sA[lc + 3][lr] = qa.w;
        sB[lc + 0][lr] = va.x; sB[lc + 1][lr] = va.y; sB[lc + 2][lr] = va.z; sB[lc + 3][lr] = va.w;
        __syncthreads();
#pragma unroll
        for (int k = 0; k < BK; ++k) {
            float4 a4 = *(const float4*)&sA[k][ty << 2];
            float4 b4 = *(const float4*)&sB[k][tx << 2];
            float a[4] = {a4.x, a4.y, a4.z, a4.w};
            float bb[4] = {b4.x, b4.y, b4.z, b4.w};
#pragma unroll
            for (int i = 0; i < 4; ++i)
#pragma unroll
                for (int j = 0; j < 4; ++j) acc[i][j] = fmaf(a[i], bb[j], acc[i][j]);
        }
    }
    const int r0 = blockIdx.x * BM + (ty << 2), c0 = blockIdx.y * BN + (tx << 2);
#pragma unroll
    for (int i = 0; i < 4; ++i) {
        float4 o = {acc[i][0], acc[i][1], acc[i][2], acc[i][3]};
        *(float4*)(Sb + (size_t)(r0 + i) * LK + c0) = o;
    }
}

__global__ __launch_bounds__(256) void gemm_pv(const float* __restrict__ P,
                                               const float* __restrict__ V,
                                               float* __restrict__ C) {
    __shared__ __align__(16) float sA[BK][BM + PAD];
    __shared__ __align__(16) float sB[BK][BN + PAD];
    const int b = blockIdx.z;
    const float* Pb = P + (size_t)b * LQ * LK + (size_t)blockIdx.x * BM * LK;
    const float* Vb = V + (size_t)b * LK * DD;
    float*       Cb = C + (size_t)b * LQ * DD;
    const int tid = threadIdx.x;
    const int tx = tid & 15, ty = tid >> 4;
    const int lr = tid >> 2, lc = (tid & 3) << 2;
    const int bkr = tid >> 4, bcg = (tid & 15) << 2;
    const int n0 = blockIdx.y * BN;
    float acc[4][4] = {};
    for (int k0 = 0; k0 < LK; k0 += BK) {
        float4 pa = *(const float4*)(Pb + (size_t)lr * LK + k0 + lc);
        float4 vb = *(const float4*)(Vb + (size_t)(k0 + bkr) * DD + n0 + bcg);
        __syncthreads();
        sA[lc + 0][lr] = pa.x; sA[lc + 1][lr] = pa.y; sA[lc + 2][lr] = pa.z; sA[lc + 3][lr] = pa.w;
        *(float4*)&sB[bkr][bcg] = vb;
        __syncthreads();
#pragma unroll
        for (int k = 0; k < BK; ++k) {
            float4 a4 = *(const float4*)&sA[k][ty << 2];
            float4 b4 = *(const float4*)&sB[k][tx << 2];
            float a[4] = {a4.x, a4.y, a4.z, a4.w};
            float bb[4] = {b4.x, b4.y, b4.z, b4.w};
#pragma unroll
            for (int i = 0; i < 4; ++i)
#pragma unroll
                for (int j = 0; j < 4; ++j) acc[i][j] = fmaf(a[i], bb[j], acc[i][j]);
        }
    }
    const int r0 = blockIdx.x * BM + (ty << 2), c0 = n0 + (tx << 2);
#pragma unroll
    for (int i = 0; i < 4; ++i) {
        float4 o = {acc[i][0], acc[i][1], acc[i][2], acc[i][3]};
        *(float4*)(Cb + (size_t)(r0 + i) * DD + c0) = o;
    }
}

// ---------------------------------------------------------------------------
extern "C" void kernel_launch(void* const* d_in, const int* in_sizes, int n_in,
                              void* d_out, int out_size, void* d_ws, size_t ws_size,
                              hipStream_t stream) {
    const float* Q = (const float*)d_in[0];
    const float* V = (const float*)d_in[1];

    float* ctx  = (float*)d_out;                       // [16,1024,512]
    float* attn = ctx + (size_t)BATCH * LQ * DD;       // [16,1024,1024]

    const size_t qv_elems = (size_t)BATCH * LQ * DD;   // 8.4M u32 = 33.55 MB
    const size_t p_elems  = (size_t)BATCH * LQ * LK;   // 16.8M u32 = 67.1 MB
    const size_t need_new = (3 * qv_elems + p_elems) * sizeof(float);  // 167.8 MB

    if (ws_size >= need_new) {
        float* Qhl  = (float*)d_ws;
        float* Vhl  = Qhl  + qv_elems;
        float* Vthl = Vhl  + qv_elems;
        float* Phl  = Vthl + qv_elems;
        pack_q<<<dim3(BATCH * LQ * DD / (8 * 256)), 256, 0, stream>>>(Q, Qhl);
        transpose_pack_v<<<dim3(DD / 32, LK / 32, BATCH), 256, 0, stream>>>(V, Vhl, Vthl);
        // S = Q @ V^T : A = Qhl [1024,512], B = Vhl [1024,512]
        gemm_bf16split<DD, LK, 3><<<dim3(8, 8, BATCH), 256, 0, stream>>>(Qhl, Vhl, attn);
        softmax_rows_pack2<<<dim3(BATCH * LQ / 4), 256, 0, stream>>>(attn, Phl);
        // ctx = P @ V : A = Phl [1024,1024] (hi used), B = Vthl [512,1024]
        gemm_bf16split<LK, DD, 2><<<dim3(8, 4, BATCH), 256, 0, stream>>>(Phl, Vthl, ctx);
    } else if (ws_size >= qv_elems * sizeof(float)) {
        float* Vt = (float*)d_ws;
        transpose_v<<<dim3(DD / 32, LK / 32, BATCH), 256, 0, stream>>>(V, Vt);
        gemm_f32split<DD, LK><<<dim3(8, 8, BATCH), 256, 0, stream>>>(Q, V, attn);
        softmax_rows<<<dim3(BATCH * LQ), 256, 0, stream>>>(attn);
        gemm_f32split<LK, DD><<<dim3(8, 4, BATCH), 256, 0, stream>>>(attn, Vt, ctx);
    } else {
        gemm_qvt<<<dim3(LQ / BM, LK / BN, BATCH), 256, 0, stream>>>(Q, V, attn);
        softmax_rows<<<dim3(BATCH * LQ), 256, 0, stream>>>(attn);
        gemm_pv<<<dim3(LQ / BM, DD / BN, BATCH), 256, 0, stream>>>(attn, V, ctx);
    }
}

// Round 4
// 257.040 us; speedup vs baseline: 1.1547x; 1.1440x over previous
//
#include <hip/hip_runtime.h>

#define BATCH 16
#define LQ    1024
#define LK    1024
#define DD    512

typedef unsigned int u32;
typedef short short8 __attribute__((ext_vector_type(8)));
typedef float f32x4 __attribute__((ext_vector_type(4)));
typedef u32 u32x2 __attribute__((ext_vector_type(2)));
typedef u32 u32x4 __attribute__((ext_vector_type(4)));
#define AS1 __attribute__((address_space(1)))
#define AS3 __attribute__((address_space(3)))

// ---------------------------------------------------------------------------
// split fp32 pair -> packed bf16 hi (truncation) and bf16 lo (= x - hi)
// ---------------------------------------------------------------------------
__device__ __forceinline__ void split2(float x0, float x1, u32& hp, u32& lp) {
    u32 u0 = __float_as_uint(x0), u1 = __float_as_uint(x1);
    hp = __builtin_amdgcn_perm(u1, u0, 0x07060302u);   // (bf16(x0), bf16(x1))
    float l0 = x0 - __uint_as_float(u0 & 0xffff0000u);
    float l1 = x1 - __uint_as_float(u1 & 0xffff0000u);
    lp = __builtin_amdgcn_perm(__float_as_uint(l1), __float_as_uint(l0), 0x07060302u);
}

// 8 fp32 (f0 = k 8q..8q+3, f1 = 8q+4..8q+7) -> hi + lo bf16 frags
__device__ __forceinline__ void mk_frags(f32x4 f0, f32x4 f1, short8& h, short8& l) {
    union { u32 u[4]; short8 s; } H, L;
    split2(f0[0], f0[1], H.u[0], L.u[0]);
    split2(f0[2], f0[3], H.u[1], L.u[1]);
    split2(f1[0], f1[1], H.u[2], L.u[2]);
    split2(f1[2], f1[3], H.u[3], L.u[3]);
    h = H.s; l = L.s;
}

// hi-only variant (4 perms, no lo)
__device__ __forceinline__ short8 hi8(f32x4 f0, f32x4 f1) {
    union { u32 u[4]; short8 s; } H;
    H.u[0] = __builtin_amdgcn_perm(__float_as_uint(f0[1]), __float_as_uint(f0[0]), 0x07060302u);
    H.u[1] = __builtin_amdgcn_perm(__float_as_uint(f0[3]), __float_as_uint(f0[2]), 0x07060302u);
    H.u[2] = __builtin_amdgcn_perm(__float_as_uint(f1[1]), __float_as_uint(f1[0]), 0x07060302u);
    H.u[3] = __builtin_amdgcn_perm(__float_as_uint(f1[3]), __float_as_uint(f1[2]), 0x07060302u);
    return H.s;
}

// Packed hi/lo layout for a logical [R x K] fp32 matrix (same byte count):
// per row, per 32-k chunk: 16 u32 of hi pairs (k ascending), then 16 u32 of lo.

// ---------------------------------------------------------------------------
// V [LK x DD] -> packed Vhl [LK x DD] and packed Vthl [DD x LK], per batch.
// grid (DD/32, LK/32, BATCH), 256 threads, 32x32 tile via LDS.
// ---------------------------------------------------------------------------
__global__ __launch_bounds__(256) void transpose_pack_v(const float* __restrict__ V,
                                                        float* __restrict__ Vhl,
                                                        float* __restrict__ Vthl) {
    __shared__ float tile[32][33];
    const int b = blockIdx.z;
    const int c0 = blockIdx.x * 32;   // d
    const int r0 = blockIdx.y * 32;   // kv
    const int t = threadIdx.x;
    const int r = t >> 3, c4 = (t & 7) * 4;
    const float* Vb = V + (size_t)b * LK * DD;
    f32x4 f = *(const f32x4*)(Vb + (size_t)(r0 + r) * DD + c0 + c4);

    // row-major packed (GEMM1 B operand): row = kv, k = d
    u32 h0, l0, h1, l1;
    split2(f[0], f[1], h0, l0);
    split2(f[2], f[3], h1, l1);
    u32* vb = (u32*)Vhl + (size_t)b * LK * DD + (size_t)(r0 + r) * DD
            + (c0 >> 5) * 32 + (t & 7) * 2;
    *(u32x2*)vb        = u32x2{h0, h1};
    *(u32x2*)(vb + 16) = u32x2{l0, l1};

    tile[r][c4 + 0] = f[0]; tile[r][c4 + 1] = f[1];
    tile[r][c4 + 2] = f[2]; tile[r][c4 + 3] = f[3];
    __syncthreads();

    // transposed packed (GEMM2 B operand): row = d, k = kv
    const int n = t >> 3, k4 = (t & 7) * 4;
    f32x4 o = {tile[k4 + 0][n], tile[k4 + 1][n], tile[k4 + 2][n], tile[k4 + 3][n]};
    split2(o[0], o[1], h0, l0);
    split2(o[2], o[3], h1, l1);
    u32* vtb = (u32*)Vthl + (size_t)b * DD * LK + (size_t)(c0 + n) * LK
             + (r0 >> 5) * 32 + (t & 7) * 2;
    *(u32x2*)vtb        = u32x2{h0, h1};
    *(u32x2*)(vtb + 16) = u32x2{l0, l1};
}

// ---------------------------------------------------------------------------
// Split-bf16 MFMA GEMM:  C[1024 x NG] = A[1024 x KG] * B[NG x KG]^T  per batch
//   B is always pre-packed hi/lo (Vhl / Vthl).
//   PACKA=false: A staged as raw fp32 rows (same 128 B/row, same swizzle),
//                frags built in-register (split work fits the load-wait slack).
//   NPROD=3: acc += Ah*Bh + Ah*Bl + Al*Bh    (full split product, Q@V^T)
//   NPROD=2: acc += Ah*Bh + Ah*Bl            (P in [0,1]: Al term ~1.5e-3, P@V)
//
// 128x128 tile, BK=32, 4 waves, double-buffered LDS, one barrier per K-step,
// prefetch issued before compute. LDS rows = 8 x 16B chunks, phys = log ^ (row&7).
// XCD-aware block swizzle: each XCD gets a contiguous chunk of tile space
// (2 whole batches) so A/B panels stay XCD-L2-resident. Bijective (nwg%8==0).
// ---------------------------------------------------------------------------
template <int KG, int NG, int NPROD, bool PACKA>
__global__ __launch_bounds__(256) void gemm_bf16split(const float* __restrict__ A,
                                                      const float* __restrict__ B,
                                                      float* __restrict__ C) {
    __shared__ float sm[2][2][128 * 32];   // [buf][operand][row*32 + float] = 64 KB

    constexpr int GY  = NG / 128;              // 8 (GEMM1) or 4 (GEMM2)
    constexpr int GYS = (GY == 8) ? 3 : 2;
    const u32 wgid = blockIdx.x + (blockIdx.y << 3) + ((u32)blockIdx.z << (3 + GYS));
    const u32 nwg  = (u32)(8 * GY * BATCH);
    const u32 swz  = (wgid & 7) * (nwg >> 3) + (wgid >> 3);
    const int bm0  = (swz & 7) * 128;
    const int bn0  = ((swz >> 3) & (GY - 1)) * 128;
    const int b    = swz >> (3 + GYS);

    const int tid = threadIdx.x;
    const int w   = tid >> 6;
    const int lane = tid & 63;

    // staging: waves 0,1 -> A rows [woff,+64); waves 2,3 -> B rows [woff,+64)
    const int op   = w >> 1;
    const int woff = (w & 1) * 64;
    const float* gsrc = (op == 0)
        ? A + (size_t)b * 1024 * KG + (size_t)(bm0 + woff) * KG
        : B + (size_t)b * NG * KG   + (size_t)(bn0 + woff) * KG;
    gsrc += (size_t)(lane >> 3) * KG + (size_t)(((lane & 7) ^ (lane >> 3)) * 4);

    const int mf = lane & 15, q = lane >> 4;
    const int e  = mf & 7;
    const int ch = ((q)     ^ e) * 4;   // packed: float offset of hi subchunk q
    const int cl = ((4 + q) ^ e) * 4;   // packed: float offset of lo subchunk q
    const int c0 = ((2 * q)     ^ e) * 4;   // raw fp32: logical chunk 2q
    const int c1 = ((2 * q + 1) ^ e) * 4;   // raw fp32: logical chunk 2q+1
    const int wm = (w & 1) * 64, wn = (w >> 1) * 64;

    f32x4 acc[4][4] = {};

    auto stage = [&](int pb, int k) {
#pragma unroll
        for (int t = 0; t < 8; ++t)
            __builtin_amdgcn_global_load_lds((const AS1 u32*)(gsrc + k + (size_t)t * 8 * KG),
                                             (AS3 u32*)(&sm[pb][op][(woff + t * 8) * 32]),
                                             16, 0, 0);
    };

    stage(0, 0);
    int p = 0;
    for (int k0 = 0; k0 < KG; k0 += 32) {
        __syncthreads();                 // drains prefetch into sm[p]; protects sm[p^1]
        if (k0 + 32 < KG) stage(p ^ 1, k0 + 32);

        const float* As = &sm[p][0][0];
        const float* Bs = &sm[p][1][0];
        short8 ah[4], al[4], bh[4], bl[4];
#pragma unroll
        for (int i = 0; i < 4; ++i) {
            const int ra = (wm + mf + i * 16) * 32;
            if constexpr (PACKA) {
                ah[i] = *(const short8*)&As[ra + ch];
                if constexpr (NPROD == 3) al[i] = *(const short8*)&As[ra + cl];
            } else {
                f32x4 f0 = *(const f32x4*)&As[ra + c0];
                f32x4 f1 = *(const f32x4*)&As[ra + c1];
                if constexpr (NPROD == 3) mk_frags(f0, f1, ah[i], al[i]);
                else                      ah[i] = hi8(f0, f1);
            }
            const int rb = (wn + mf + i * 16) * 32;
            bh[i] = *(const short8*)&Bs[rb + ch];
            bl[i] = *(const short8*)&Bs[rb + cl];
        }
#pragma unroll
        for (int i = 0; i < 4; ++i)
#pragma unroll
            for (int j = 0; j < 4; ++j) {
                acc[i][j] = __builtin_amdgcn_mfma_f32_16x16x32_bf16(ah[i], bh[j], acc[i][j], 0, 0, 0);
                acc[i][j] = __builtin_amdgcn_mfma_f32_16x16x32_bf16(ah[i], bl[j], acc[i][j], 0, 0, 0);
                if constexpr (NPROD == 3)
                    acc[i][j] = __builtin_amdgcn_mfma_f32_16x16x32_bf16(al[i], bh[j], acc[i][j], 0, 0, 0);
            }
        p ^= 1;
    }

    // epilogue: C/D layout col = lane&15, row = q*4 + reg  [m89-verified]
    float* Cb = C + (size_t)b * 1024 * NG + (size_t)bm0 * NG + bn0;
#pragma unroll
    for (int i = 0; i < 4; ++i)
#pragma unroll
        for (int j = 0; j < 4; ++j)
#pragma unroll
            for (int r = 0; r < 4; ++r)
                Cb[(size_t)(wm + i * 16 + q * 4 + r) * NG + wn + j * 16 + mf] = acc[i][j][r];
}

// ---------------------------------------------------------------------------
// Barrier-free row softmax in place: one wave per row (16 floats/lane in regs),
// 4 rows/block, pure shuffle reductions. 16384 rows -> 4096 blocks.
// ---------------------------------------------------------------------------
__global__ __launch_bounds__(256) void softmax_rows2(float* __restrict__ S) {
    const int t = threadIdx.x;
    const int wave = t >> 6, lane = t & 63;
    const size_t row = (size_t)blockIdx.x * 4 + wave;
    float* p = S + row * LK;
    f32x4 v[4];
#pragma unroll
    for (int c = 0; c < 4; ++c)
        v[c] = *(const f32x4*)(p + lane * 4 + c * 256);
    float m = -1e30f;
#pragma unroll
    for (int c = 0; c < 4; ++c)
        m = fmaxf(m, fmaxf(fmaxf(v[c][0], v[c][1]), fmaxf(v[c][2], v[c][3])));
#pragma unroll
    for (int off = 1; off < 64; off <<= 1) m = fmaxf(m, __shfl_xor(m, off, 64));
    float s = 0.0f;
#pragma unroll
    for (int c = 0; c < 4; ++c) {
        v[c][0] = __expf(v[c][0] - m);
        v[c][1] = __expf(v[c][1] - m);
        v[c][2] = __expf(v[c][2] - m);
        v[c][3] = __expf(v[c][3] - m);
        s += (v[c][0] + v[c][1]) + (v[c][2] + v[c][3]);
    }
#pragma unroll
    for (int off = 1; off < 64; off <<= 1) s += __shfl_xor(s, off, 64);
    const float inv = 1.0f / s;
#pragma unroll
    for (int c = 0; c < 4; ++c) {
        v[c] = v[c] * inv;
        *(f32x4*)(p + lane * 4 + c * 256) = v[c];
    }
}

// ===========================================================================
// Fallback path B (tiny ws): plain fp32 tiled GEMMs + block softmax
// ===========================================================================
constexpr int BM = 64, BN = 64, BK = 16, PAD = 4;

__global__ __launch_bounds__(256) void softmax_rows(float* __restrict__ S) {
    float* p = S + (size_t)blockIdx.x * LK;
    const int t = threadIdx.x;
    float4 v = *(float4*)(p + (t << 2));
    float m = fmaxf(fmaxf(v.x, v.y), fmaxf(v.z, v.w));
#pragma unroll
    for (int off = 1; off < 64; off <<= 1) m = fmaxf(m, __shfl_xor(m, off, 64));
    __shared__ float redm[4]; __shared__ float reds[4];
    const int wave = t >> 6, lane = t & 63;
    if (lane == 0) redm[wave] = m;
    __syncthreads();
    m = fmaxf(fmaxf(redm[0], redm[1]), fmaxf(redm[2], redm[3]));
    v.x = __expf(v.x - m); v.y = __expf(v.y - m);
    v.z = __expf(v.z - m); v.w = __expf(v.w - m);
    float s = (v.x + v.y) + (v.z + v.w);
#pragma unroll
    for (int off = 1; off < 64; off <<= 1) s += __shfl_xor(s, off, 64);
    if (lane == 0) reds[wave] = s;
    __syncthreads();
    s = (reds[0] + reds[1]) + (reds[2] + reds[3]);
    const float inv = 1.0f / s;
    v.x *= inv; v.y *= inv; v.z *= inv; v.w *= inv;
    *(float4*)(p + (t << 2)) = v;
}

__global__ __launch_bounds__(256) void gemm_qvt(const float* __restrict__ Q,
                                                const float* __restrict__ V,
                                                float* __restrict__ S) {
    __shared__ __align__(16) float sA[BK][BM + PAD];
    __shared__ __align__(16) float sB[BK][BN + PAD];
    const int b = blockIdx.z;
    const float* Qb = Q + (size_t)b * LQ * DD + (size_t)blockIdx.x * BM * DD;
    const float* Vb = V + (size_t)b * LK * DD + (size_t)blockIdx.y * BN * DD;
    float*       Sb = S + (size_t)b * LQ * LK;
    const int tid = threadIdx.x;
    const int tx = tid & 15, ty = tid >> 4;
    const int lr = tid >> 2, lc = (tid & 3) << 2;
    float acc[4][4] = {};
    for (int k0 = 0; k0 < DD; k0 += BK) {
        float4 qa = *(const float4*)(Qb + (size_t)lr * DD + k0 + lc);
        float4 va = *(const float4*)(Vb + (size_t)lr * DD + k0 + lc);
        __syncthreads();
        sA[lc + 0][lr] = qa.x; sA[lc + 1][lr] = qa.y; sA[lc + 2][lr] = qa.z; sA[lc + 3][lr] = qa.w;
        sB[lc + 0][lr] = va.x; sB[lc + 1][lr] = va.y; sB[lc + 2][lr] = va.z; sB[lc + 3][lr] = va.w;
        __syncthreads();
#pragma unroll
        for (int k = 0; k < BK; ++k) {
            float4 a4 = *(const float4*)&sA[k][ty << 2];
            float4 b4 = *(const float4*)&sB[k][tx << 2];
            float a[4] = {a4.x, a4.y, a4.z, a4.w};
            float bb[4] = {b4.x, b4.y, b4.z, b4.w};
#pragma unroll
            for (int i = 0; i < 4; ++i)
#pragma unroll
                for (int j = 0; j < 4; ++j) acc[i][j] = fmaf(a[i], bb[j], acc[i][j]);
        }
    }
    const int r0 = blockIdx.x * BM + (ty << 2), c0 = blockIdx.y * BN + (tx << 2);
#pragma unroll
    for (int i = 0; i < 4; ++i) {
        float4 o = {acc[i][0], acc[i][1], acc[i][2], acc[i][3]};
        *(float4*)(Sb + (size_t)(r0 + i) * LK + c0) = o;
    }
}

__global__ __launch_bounds__(256) void gemm_pv(const float* __restrict__ P,
                                               const float* __restrict__ V,
                                               float* __restrict__ C) {
    __shared__ __align__(16) float sA[BK][BM + PAD];
    __shared__ __align__(16) float sB[BK][BN + PAD];
    const int b = blockIdx.z;
    const float* Pb = P + (size_t)b * LQ * LK + (size_t)blockIdx.x * BM * LK;
    const float* Vb = V + (size_t)b * LK * DD;
    float*       Cb = C + (size_t)b * LQ * DD;
    const int tid = threadIdx.x;
    const int tx = tid & 15, ty = tid >> 4;
    const int lr = tid >> 2, lc = (tid & 3) << 2;
    const int bkr = tid >> 4, bcg = (tid & 15) << 2;
    const int n0 = blockIdx.y * BN;
    float acc[4][4] = {};
    for (int k0 = 0; k0 < LK; k0 += BK) {
        float4 pa = *(const float4*)(Pb + (size_t)lr * LK + k0 + lc);
        float4 vb = *(const float4*)(Vb + (size_t)(k0 + bkr) * DD + n0 + bcg);
        __syncthreads();
        sA[lc + 0][lr] = pa.x; sA[lc + 1][lr] = pa.y; sA[lc + 2][lr] = pa.z; sA[lc + 3][lr] = pa.w;
        *(float4*)&sB[bkr][bcg] = vb;
        __syncthreads();
#pragma unroll
        for (int k = 0; k < BK; ++k) {
            float4 a4 = *(const float4*)&sA[k][ty << 2];
            float4 b4 = *(const float4*)&sB[k][tx << 2];
            float a[4] = {a4.x, a4.y, a4.z, a4.w};
            float bb[4] = {b4.x, b4.y, b4.z, b4.w};
#pragma unroll
            for (int i = 0; i < 4; ++i)
#pragma unroll
                for (int j = 0; j < 4; ++j) acc[i][j] = fmaf(a[i], bb[j], acc[i][j]);
        }
    }
    const int r0 = blockIdx.x * BM + (ty << 2), c0 = n0 + (tx << 2);
#pragma unroll
    for (int i = 0; i < 4; ++i) {
        float4 o = {acc[i][0], acc[i][1], acc[i][2], acc[i][3]};
        *(float4*)(Cb + (size_t)(r0 + i) * DD + c0) = o;
    }
}

// ---------------------------------------------------------------------------
extern "C" void kernel_launch(void* const* d_in, const int* in_sizes, int n_in,
                              void* d_out, int out_size, void* d_ws, size_t ws_size,
                              hipStream_t stream) {
    const float* Q = (const float*)d_in[0];
    const float* V = (const float*)d_in[1];

    float* ctx  = (float*)d_out;                       // [16,1024,512]
    float* attn = ctx + (size_t)BATCH * LQ * DD;       // [16,1024,1024]

    const size_t qv_elems = (size_t)BATCH * LQ * DD;   // 8.4M floats = 33.55 MB
    const size_t need = 2 * qv_elems * sizeof(float);  // Vhl + Vthl = 67.1 MB

    if (ws_size >= need) {
        float* Vhl  = (float*)d_ws;
        float* Vthl = Vhl + qv_elems;
        transpose_pack_v<<<dim3(DD / 32, LK / 32, BATCH), 256, 0, stream>>>(V, Vhl, Vthl);
        // S = Q @ V^T : A = Q fp32 (split in-kernel), B = Vhl packed
        gemm_bf16split<DD, LK, 3, false><<<dim3(8, 8, BATCH), 256, 0, stream>>>(Q, Vhl, attn);
        softmax_rows2<<<dim3(BATCH * LQ / 4), 256, 0, stream>>>(attn);
        // ctx = P @ V : A = attn fp32 (hi extracted in-kernel), B = Vthl packed
        gemm_bf16split<LK, DD, 2, false><<<dim3(8, 4, BATCH), 256, 0, stream>>>(attn, Vthl, ctx);
    } else {
        gemm_qvt<<<dim3(LQ / BM, LK / BN, BATCH), 256, 0, stream>>>(Q, V, attn);
        softmax_rows<<<dim3(BATCH * LQ), 256, 0, stream>>>(attn);
        gemm_pv<<<dim3(LQ / BM, DD / BN, BATCH), 256, 0, stream>>>(attn, V, ctx);
    }
}